// Round 2
// baseline (318.044 us; speedup 1.0000x reference)
//
#include <hip/hip_runtime.h>

typedef unsigned short u16;
typedef unsigned int   u32;
typedef __attribute__((ext_vector_type(8))) __bf16 bf16x8;
typedef __attribute__((ext_vector_type(4))) float  f32x4;

#define L_SEQ  2048
#define BATCH  8
#define DIM    1024
#define ROWS   (L_SEQ*BATCH)     /* 16384 */
#define N3     (3*DIM)           /* 3072  */
#define NCHUNK 32
#define LCHUNK (L_SEQ/NCHUNK)    /* 64    */
#define NCHAIN (BATCH*DIM)       /* 8192  */

__device__ __forceinline__ float b2f(u16 h) {            // bf16 -> f32 exact
  return __builtin_bit_cast(float, (u32)h << 16);
}
__device__ __forceinline__ u32 pk2(float a, float b) {   // pack 2 f32 -> 2 bf16 (RNE)
  u32 r;
  asm("v_cvt_pk_bf16_f32 %0, %1, %2" : "=v"(r) : "v"(a), "v"(b));
  return r;
}
__device__ __forceinline__ u16 f2b(float f) {            // scalar f32 -> bf16 RNE
  u32 u = __builtin_bit_cast(u32, f);
  return (u16)((u + 0x7fffu + ((u >> 16) & 1u)) >> 16);
}

// ---------------- K1: GEMM C = A * B^T (bf16 MFMA, inline f32->bf16 staging) --
// A: ROWS x DIM f32 (x), B: N3 x DIM f32 (W), C: ROWS x N3 bf16
// sigmoid fused into epilogue for f/r column blocks.
__global__ __launch_bounds__(256) void k_gemm(const float* __restrict__ A,
                                              const float* __restrict__ B,
                                              u16* __restrict__ C) {
  __shared__ u16 lds[8192];                       // A tile 128x32 | B tile 128x32
  const int tid  = threadIdx.x;
  const int lane = tid & 63;
  const int wid  = tid >> 6;                      // 4 waves: 2x2 of 64x64
  const int wm = wid >> 1, wn = wid & 1;
  const int lr = lane & 15, lk = lane >> 4;
  const int mBase = blockIdx.y << 7;
  const int nBase = blockIdx.x << 7;

  f32x4 acc[4][4] = {};

  const int aoff = (wm * 64 + lr) * 32 + lk * 8;
  const int boff = 4096 + (wn * 64 + lr) * 32 + lk * 8;

  for (int k0 = 0; k0 < DIM; k0 += 32) {
    // stage: 1024 float4 loads total (A 128x32 + B 128x32), 4 per thread/side
#pragma unroll
    for (int q = 0; q < 4; ++q) {
      const int i  = q * 256 + tid;               // 0..1023
      const int rr = i >> 3;                      // 0..127
      const int cc = (i & 7) << 2;                // 0,4,...,28
      float4 va = *(const float4*)(A + (size_t)(mBase + rr) * DIM + k0 + cc);
      float4 vb = *(const float4*)(B + (size_t)(nBase + rr) * DIM + k0 + cc);
      uint2 pa; pa.x = pk2(va.x, va.y); pa.y = pk2(va.z, va.w);
      uint2 pb; pb.x = pk2(vb.x, vb.y); pb.y = pk2(vb.z, vb.w);
      *(uint2*)&lds[rr * 32 + cc] = pa;
      *(uint2*)&lds[4096 + rr * 32 + cc] = pb;
    }
    __syncthreads();                              // LDS tile ready
    bf16x8 av[4], bv[4];
#pragma unroll
    for (int m = 0; m < 4; ++m) av[m] = *(const bf16x8*)&lds[aoff + m * 512];
#pragma unroll
    for (int n = 0; n < 4; ++n) bv[n] = *(const bf16x8*)&lds[boff + n * 512];
#pragma unroll
    for (int m = 0; m < 4; ++m)
#pragma unroll
      for (int n = 0; n < 4; ++n)
        acc[m][n] = __builtin_amdgcn_mfma_f32_16x16x32_bf16(av[m], bv[n], acc[m][n], 0, 0, 0);
    __syncthreads();                              // protect LDS before next stage
  }

  const bool act = (nBase >= DIM);                // f and r columns -> sigmoid
#pragma unroll
  for (int m = 0; m < 4; ++m) {
    const int row0 = mBase + wm * 64 + m * 16 + lk * 4;
#pragma unroll
    for (int n = 0; n < 4; ++n) {
      const int col = nBase + wn * 64 + n * 16 + lr;
#pragma unroll
      for (int j = 0; j < 4; ++j) {
        float v = acc[m][n][j];
        if (act) v = 1.f / (1.f + __expf(-v));
        C[(size_t)(row0 + j) * N3 + col] = f2b(v);
      }
    }
  }
}

// ---------------- K2: chunk-local affine coefficients (P = prod f, V = scan(0))
__global__ void k_scanA(const u16* __restrict__ ufr, float* __restrict__ P,
                        float* __restrict__ V) {
  int g = blockIdx.x * 256 + threadIdx.x;         // 0..262143
  int j = g >> 13;                                // chunk (NCHAIN = 2^13)
  int chain = g & (NCHAIN - 1);
  int b = chain >> 10;
  int d = chain & (DIM - 1);
  const u16* p = ufr + (size_t)((j * LCHUNK) * BATCH + b) * N3 + d;
  float prod = 1.f, v = 0.f;
  for (int t = 0; t < LCHUNK; ++t) {
    float u = b2f(p[0]);
    float f = b2f(p[DIM]);                        // sigmoid applied in K1 epilogue
    v = f * v + (1.f - f) * u;
    prod *= f;
    p += BATCH * N3;
  }
  P[g] = prod; V[g] = v;
}

// ---------------- K3: sequential combine over 32 chunks -> chunk-start states
__global__ void k_scanB(const float* __restrict__ c0, const float* __restrict__ P,
                        const float* __restrict__ V, float* __restrict__ S,
                        float* __restrict__ lastc) {
  int chain = blockIdx.x * 256 + threadIdx.x;     // 0..8191  ( = b*DIM + d )
  float c = c0[chain];
  for (int j = 0; j < NCHUNK; ++j) {
    S[j * NCHAIN + chain] = c;
    c = P[j * NCHAIN + chain] * c + V[j * NCHAIN + chain];
  }
  lastc[chain] = c;                               // f32 output 1
}

// ---------------- K4: fused chunk replay + hs + gelu(erf) + LayerNorm -> f32 out
// one block per (chunk j, batch b); 1024 threads = one per d; 64 timesteps.
__global__ __launch_bounds__(1024) void k_scanln(const u16* __restrict__ ufr,
                                                 const float* __restrict__ S,
                                                 const float* __restrict__ x,
                                                 const float* __restrict__ lnw,
                                                 const float* __restrict__ lnb,
                                                 float* __restrict__ out) {
  const int j = blockIdx.x >> 3;                  // chunk 0..31
  const int b = blockIdx.x & 7;                   // batch 0..7
  const int d = threadIdx.x;                      // 0..1023
  const int lane = d & 63, wid = d >> 6;          // 16 waves

  float c = S[j * NCHAIN + b * DIM + d];
  const float wgt = lnw[d];
  const float bia = lnb[d];

  const u16*   pu = ufr + (size_t)((j * LCHUNK) * BATCH + b) * N3 + d;
  const float* px = x   + (size_t)((j * LCHUNK) * BATCH + b) * DIM + d;
  float*       po = out + (size_t)((j * LCHUNK) * BATCH + b) * DIM + d;

  __shared__ float red1[16], red2[16];

  for (int t = 0; t < LCHUNK; ++t) {
    float u = b2f(pu[0]);
    float f = b2f(pu[DIM]);
    float r = b2f(pu[2 * DIM]);
    c = f * c + (1.f - f) * u;
    float xx = *px;
    float hs = r * tanhf(c) + (1.f - r) * xx;
    float g  = 0.5f * hs * (1.f + erff(hs * 0.70710678118654752f));

    float s1 = g, s2 = g * g;
#pragma unroll
    for (int off = 32; off > 0; off >>= 1) {
      s1 += __shfl_down(s1, off, 64);
      s2 += __shfl_down(s2, off, 64);
    }
    if (lane == 0) { red1[wid] = s1; red2[wid] = s2; }
    __syncthreads();
    float S1 = 0.f, S2 = 0.f;
#pragma unroll
    for (int w = 0; w < 16; ++w) { S1 += red1[w]; S2 += red2[w]; }
    float mu  = S1 * (1.f / DIM);
    float var = S2 * (1.f / DIM) - mu * mu;
    float inv = rsqrtf(var + 1e-5f);
    *po = (g - mu) * inv * wgt + bia;
    __syncthreads();                              // red[] reuse next t

    pu += BATCH * N3;
    px += BATCH * DIM;
    po += BATCH * DIM;
  }
}

extern "C" void kernel_launch(void* const* d_in, const int* in_sizes, int n_in,
                              void* d_out, int out_size, void* d_ws, size_t ws_size,
                              hipStream_t stream) {
  (void)in_sizes; (void)n_in; (void)out_size; (void)ws_size;
  const float* x   = (const float*)d_in[0];
  const float* c0  = (const float*)d_in[1];
  const float* W   = (const float*)d_in[2];
  const float* lnw = (const float*)d_in[3];
  const float* lnb = (const float*)d_in[4];
  float* out   = (float*)d_out;                   // (L,B,D) f32
  float* lastc = out + (size_t)ROWS * DIM;        // (B,D)   f32

  // ws layout (total 103,809,024 B ~= 99 MB):
  //   [0, 100663296)            ufr bf16  ROWS x 3072  (u | sig(f) | sig(r))
  //   [100663296, +1 MiB)       P  f32  (NCHUNK x NCHAIN)
  //   [101711872, +1 MiB)       V  f32
  //   [102760448, +1 MiB)       S  f32  chunk-start states
  char* ws = (char*)d_ws;
  u16*   ufr = (u16*)ws;
  float* P   = (float*)(ws + 100663296);
  float* V   = (float*)(ws + 101711872);
  float* S   = (float*)(ws + 102760448);

  dim3 g1(N3 / 128, ROWS / 128);
  k_gemm<<<g1, 256, 0, stream>>>(x, W, ufr);
  k_scanA<<<(NCHUNK * NCHAIN) / 256, 256, 0, stream>>>(ufr, P, V);
  k_scanB<<<NCHAIN / 256, 256, 0, stream>>>(c0, P, V, S, lastc);
  k_scanln<<<NCHUNK * BATCH, 1024, 0, stream>>>(ufr, S, x, lnw, lnb, out);
}